// Round 3
// baseline (132.277 us; speedup 1.0000x reference)
//
#include <hip/hip_runtime.h>
#include <hip/hip_bf16.h>
#include <math.h>

#define TPB 256
#define PPT 4  // pred points per thread

// Monotone float -> unsigned key (total order preserved), for atomicMin.
__device__ __forceinline__ unsigned f2key(float f) {
  unsigned u = __float_as_uint(f);
  return (u & 0x80000000u) ? ~u : (u | 0x80000000u);
}
__device__ __forceinline__ float key2f(unsigned k) {
  unsigned u = (k & 0x80000000u) ? (k ^ 0x80000000u) : ~k;
  return __uint_as_float(u);
}

// One fused kernel. Block = (batch b, pred-chunk pc, target-chunk tc).
// Stage target chunk in LDS as (tx,ty,tz, 0.5*t^2); each thread owns PPT pred
// points, keeps min of s = 0.5*t^2 - p.t over the chunk, then atomicMin's
// key(s + 0.5*p^2) = key(d^2/2) into the per-pred slot (exact, order-free).
// tc==0 blocks also compute the ADD (asym) per-point partial sums.
// The LAST block (counter ticket) finalizes: fixed-order per-batch sums,
// sym/asym blend, scalar out. Deterministic: min is order-invariant, all
// float sums are fixed-order.
__global__ __launch_bounds__(TPB) void chamfer_fused_kernel(
    const float* __restrict__ pred, const float* __restrict__ targ,
    const float* __restrict__ sym_flag, float* __restrict__ out,
    unsigned* __restrict__ keys,     // [B*N], pre-set to 0xFFFFFFFF
    float* __restrict__ psumAsym,    // [B*predChunks]
    unsigned* __restrict__ counter,  // pre-set to 0
    int N, int B, int predChunks, int TC) {
  __shared__ float4 sh[256];

  const int blk = blockIdx.x;
  const int tc = blk % TC;
  const int rest = blk / TC;
  const int pc = rest % predChunks;
  const int b = rest / predChunks;
  const int tcSize = N / TC;  // <=256

  // Stage this target chunk into LDS.
  const float* tb = targ + ((size_t)b * N + (size_t)tc * tcSize) * 3;
  for (int i = threadIdx.x; i < tcSize; i += TPB) {
    const float tx = tb[i * 3 + 0], ty = tb[i * 3 + 1], tz = tb[i * 3 + 2];
    sh[i] = make_float4(tx, ty, tz, 0.5f * (tx * tx + ty * ty + tz * tz));
  }
  __syncthreads();

  const int predBase = pc * (TPB * PPT);
  const float* pb = pred + ((size_t)b * N + predBase) * 3;

  float npx[PPT], npy[PPT], npz[PPT], smin[PPT], hp2[PPT];
#pragma unroll
  for (int j = 0; j < PPT; ++j) {
    const int idx = j * TPB + threadIdx.x;
    const float px = pb[idx * 3 + 0];
    const float py = pb[idx * 3 + 1];
    const float pz = pb[idx * 3 + 2];
    npx[j] = -px; npy[j] = -py; npz[j] = -pz;
    hp2[j] = 0.5f * (px * px + py * py + pz * pz);
    smin[j] = 3.4e38f;
  }

#pragma unroll 4
  for (int m = 0; m < tcSize; ++m) {
    const float4 t = sh[m];  // broadcast read, conflict-free
#pragma unroll
    for (int j = 0; j < PPT; ++j) {
      const float s = fmaf(npx[j], t.x, fmaf(npy[j], t.y, fmaf(npz[j], t.z, t.w)));
      smin[j] = fminf(smin[j], s);
    }
  }

  // Merge across tc via exact atomic min of d^2/2.
  unsigned* kbase = keys + (size_t)b * N + predBase;
#pragma unroll
  for (int j = 0; j < PPT; ++j)
    atomicMin(&kbase[j * TPB + threadIdx.x], f2key(smin[j] + hp2[j]));

  // ADD (asym) term: only one tc-block per (b,pc) computes it.
  if (tc == 0) {
    const float* tq = targ + ((size_t)b * N + predBase) * 3;
    float a = 0.f;
#pragma unroll
    for (int j = 0; j < PPT; ++j) {
      const int idx = j * TPB + threadIdx.x;
      const float dx = -npx[j] - tq[idx * 3 + 0];
      const float dy = -npy[j] - tq[idx * 3 + 1];
      const float dz = -npz[j] - tq[idx * 3 + 2];
      a += sqrtf(dx * dx + dy * dy + dz * dz);
    }
#pragma unroll
    for (int off = 32; off > 0; off >>= 1) a += __shfl_down(a, off);
    __shared__ float sA[TPB / 64];
    if ((threadIdx.x & 63) == 0) sA[threadIdx.x >> 6] = a;
    __syncthreads();
    if (threadIdx.x == 0) {
      float t = 0.f;
#pragma unroll
      for (int w = 0; w < TPB / 64; ++w) t += sA[w];
      psumAsym[b * predChunks + pc] = t;
    }
  }

  // Last-block election (release fence -> ticket -> acquire fence).
  __shared__ int isLast;
  __threadfence();  // make keys/psumAsym writes agent-visible
  if (threadIdx.x == 0) {
    const unsigned old = atomicAdd(counter, 1u);
    isLast = (old == (unsigned)(gridDim.x - 1));
  }
  __syncthreads();
  if (!isLast) return;
  __threadfence();  // acquire

  // Finalize: fixed-order sums per batch, blend, mean.
  __shared__ float red[TPB / 64];
  __shared__ float bl[64];
  const int lane = threadIdx.x & 63;
  const int wave = threadIdx.x >> 6;
  const float invN = 1.0f / (float)N;
  for (int bb = 0; bb < B; ++bb) {
    float s = 0.f;
    for (int i = threadIdx.x; i < N; i += TPB) {
      const unsigned k = __hip_atomic_load(&keys[(size_t)bb * N + i],
                                           __ATOMIC_RELAXED,
                                           __HIP_MEMORY_SCOPE_AGENT);
      s += sqrtf(fmaxf(2.0f * key2f(k), 1e-12f));
    }
#pragma unroll
    for (int off = 32; off > 0; off >>= 1) s += __shfl_down(s, off);
    if (lane == 0) red[wave] = s;
    __syncthreads();
    if (threadIdx.x == 0) {
      float t = 0.f;
#pragma unroll
      for (int w = 0; w < TPB / 64; ++w) t += red[w];
      float a = 0.f;
      for (int p = 0; p < predChunks; ++p)
        a += __hip_atomic_load(&psumAsym[bb * predChunks + p], __ATOMIC_RELAXED,
                               __HIP_MEMORY_SCOPE_AGENT);
      const float f = sym_flag[bb];
      bl[bb] = f * (t * invN) + (1.f - f) * (a * invN);
    }
    __syncthreads();
  }
  if (threadIdx.x == 0) {
    float tot = 0.f;
    for (int bb = 0; bb < B; ++bb) tot += bl[bb];
    out[0] = tot / (float)B;
  }
}

extern "C" void kernel_launch(void* const* d_in, const int* in_sizes, int n_in,
                              void* d_out, int out_size, void* d_ws, size_t ws_size,
                              hipStream_t stream) {
  const float* pred = (const float*)d_in[0];
  const float* targ = (const float*)d_in[1];
  const float* sym_flag = (const float*)d_in[2];
  float* out = (float*)d_out;

  const int B = in_sizes[2];            // 16
  const int N = in_sizes[0] / (B * 3);  // 2048

  const int predChunks = N / (TPB * PPT);  // 2
  const int TC = 32;                       // 64 targets per chunk

  // ws layout: keys [B*N u32] | psumAsym [B*predChunks f32] | counter [u32]
  unsigned* keys = (unsigned*)d_ws;
  float* psumAsym = (float*)(keys + (size_t)B * N);
  unsigned* counter = (unsigned*)(psumAsym + (size_t)B * predChunks);

  hipMemsetAsync(keys, 0xFF, (size_t)B * N * sizeof(unsigned), stream);
  hipMemsetAsync(counter, 0, sizeof(unsigned), stream);

  const int grid = B * predChunks * TC;  // 1024
  chamfer_fused_kernel<<<grid, TPB, 0, stream>>>(
      pred, targ, sym_flag, out, keys, psumAsym, counter, N, B, predChunks, TC);
}

// Round 4
// 21.823 us; speedup vs baseline: 6.0614x; 6.0614x over previous
//
#include <hip/hip_runtime.h>
#include <hip/hip_bf16.h>
#include <math.h>

#define TPB 256
#define PPT 8  // pred points per thread; TPB*PPT == N == 2048

// Kernel A: block = (batch b, target-chunk tc). Stage tcSize targets in LDS
// as (tx,ty,tz, 0.5*t^2). Each thread owns 8 CONTIGUOUS pred points
// (points 8*tid .. 8*tid+7), loaded via 6 float4 loads. Inner loop: per 2
// targets, per point: 6 fma + 1 min3 (s = 0.5 t^2 - p.t is monotone in d^2).
// Writes d^2/2 = smin + 0.5 p^2 to pmin[tc][b][n] via 2 float4 stores.
// tc==0 blocks also produce the per-batch ADD (asym) sum, and block 0
// zeroes out[0] for kernel B's atomicAdd accumulation.
__global__ __launch_bounds__(TPB) void chamfer_min_kernel(
    const float* __restrict__ pred, const float* __restrict__ targ,
    float* __restrict__ pmin, float* __restrict__ psumAsym,
    float* __restrict__ out, int N, int B, int TC) {
  __shared__ float4 sh[256];
  __shared__ float raw[768];

  const int tc = blockIdx.x % TC;
  const int b = blockIdx.x / TC;
  const int tcSize = N / TC;  // 64 at TC=32 (even, <=256)

  if (blockIdx.x == 0 && threadIdx.x == 0) out[0] = 0.f;  // for B's atomics

  // Stage raw target chunk (float4 vector loads), then build (x,y,z,0.5t^2).
  const float* tb = targ + ((size_t)b * N + (size_t)tc * tcSize) * 3;
  const int nv4 = (tcSize * 3) >> 2;
  for (int i = threadIdx.x; i < nv4; i += TPB)
    ((float4*)raw)[i] = ((const float4*)tb)[i];
  __syncthreads();
  for (int i = threadIdx.x; i < tcSize; i += TPB) {
    const float tx = raw[i * 3 + 0], ty = raw[i * 3 + 1], tz = raw[i * 3 + 2];
    sh[i] = make_float4(tx, ty, tz, 0.5f * (tx * tx + ty * ty + tz * tz));
  }
  __syncthreads();

  // Load this thread's 8 contiguous pred points: 24 floats = 6 float4.
  const int pbase = threadIdx.x * PPT;  // first owned point
  float pf[24];
  {
    const float4* p4 = (const float4*)(pred + (size_t)b * N * 3);
#pragma unroll
    for (int k = 0; k < 6; ++k) {
      const float4 v = p4[threadIdx.x * 6 + k];
      pf[k * 4 + 0] = v.x; pf[k * 4 + 1] = v.y;
      pf[k * 4 + 2] = v.z; pf[k * 4 + 3] = v.w;
    }
  }
  float npx[PPT], npy[PPT], npz[PPT], hp2[PPT], smin[PPT];
#pragma unroll
  for (int j = 0; j < PPT; ++j) {
    const float px = pf[j * 3 + 0], py = pf[j * 3 + 1], pz = pf[j * 3 + 2];
    npx[j] = -px; npy[j] = -py; npz[j] = -pz;
    hp2[j] = 0.5f * (px * px + py * py + pz * pz);
    smin[j] = 3.4e38f;
  }

#pragma unroll 2
  for (int m = 0; m < tcSize; m += 2) {
    const float4 t0 = sh[m];      // broadcast, conflict-free
    const float4 t1 = sh[m + 1];
#pragma unroll
    for (int j = 0; j < PPT; ++j) {
      const float s0 = fmaf(npx[j], t0.x, fmaf(npy[j], t0.y, fmaf(npz[j], t0.z, t0.w)));
      const float s1 = fmaf(npx[j], t1.x, fmaf(npy[j], t1.y, fmaf(npz[j], t1.z, t1.w)));
      smin[j] = fminf(fminf(smin[j], s0), s1);  // -> v_min3_f32
    }
  }

  // Store d^2/2, two float4 per thread (contiguous 8 floats).
  {
    float4* dst = (float4*)(pmin + ((size_t)tc * B + b) * N + pbase);
    dst[0] = make_float4(smin[0] + hp2[0], smin[1] + hp2[1],
                         smin[2] + hp2[2], smin[3] + hp2[3]);
    dst[1] = make_float4(smin[4] + hp2[4], smin[5] + hp2[5],
                         smin[6] + hp2[6], smin[7] + hp2[7]);
  }

  // ADD (asym) per-batch sum: one tc-block per batch.
  if (tc == 0) {
    const float4* t4 = (const float4*)(targ + (size_t)b * N * 3);
    float tf[24];
#pragma unroll
    for (int k = 0; k < 6; ++k) {
      const float4 v = t4[threadIdx.x * 6 + k];
      tf[k * 4 + 0] = v.x; tf[k * 4 + 1] = v.y;
      tf[k * 4 + 2] = v.z; tf[k * 4 + 3] = v.w;
    }
    float a = 0.f;
#pragma unroll
    for (int j = 0; j < PPT; ++j) {
      const float dx = -npx[j] - tf[j * 3 + 0];
      const float dy = -npy[j] - tf[j * 3 + 1];
      const float dz = -npz[j] - tf[j * 3 + 2];
      a += sqrtf(dx * dx + dy * dy + dz * dz);
    }
#pragma unroll
    for (int off = 32; off > 0; off >>= 1) a += __shfl_down(a, off);
    __shared__ float sA[TPB / 64];
    if ((threadIdx.x & 63) == 0) sA[threadIdx.x >> 6] = a;
    __syncthreads();
    if (threadIdx.x == 0) {
      float t = 0.f;
#pragma unroll
      for (int w = 0; w < TPB / 64; ++w) t += sA[w];
      psumAsym[b] = t;
    }
  }
}

// Kernel B: block = (batch b, subblock sb). Min across TC chunks per pred
// point, sqrt, block-reduce, then one atomicAdd of the blended partial into
// out[0] (zeroed by kernel A). sb==0 also adds the asym term.
__global__ __launch_bounds__(TPB) void chamfer_reduce_kernel(
    const float* __restrict__ pmin, const float* __restrict__ psumAsym,
    const float* __restrict__ sym_flag, float* __restrict__ out,
    int N, int B, int TC, int blocksPerBatch, float invNB) {
  const int b = blockIdx.x / blocksPerBatch;
  const int sb = blockIdx.x % blocksPerBatch;
  const int i = sb * TPB + threadIdx.x;

  const size_t bnStride = (size_t)B * N;
  const size_t base = (size_t)b * N + i;
  float v = pmin[base];
  for (int tc = 1; tc < TC; ++tc)
    v = fminf(v, pmin[(size_t)tc * bnStride + base]);
  float d = sqrtf(fmaxf(2.0f * v, 1e-12f));

#pragma unroll
  for (int off = 32; off > 0; off >>= 1) d += __shfl_down(d, off);
  __shared__ float sS[TPB / 64];
  if ((threadIdx.x & 63) == 0) sS[threadIdx.x >> 6] = d;
  __syncthreads();
  if (threadIdx.x == 0) {
    float t = 0.f;
#pragma unroll
    for (int w = 0; w < TPB / 64; ++w) t += sS[w];
    const float f = sym_flag[b];
    float contrib = f * t * invNB;
    if (sb == 0) contrib += (1.f - f) * psumAsym[b] * invNB;
    atomicAdd(out, contrib);
  }
}

extern "C" void kernel_launch(void* const* d_in, const int* in_sizes, int n_in,
                              void* d_out, int out_size, void* d_ws, size_t ws_size,
                              hipStream_t stream) {
  const float* pred = (const float*)d_in[0];
  const float* targ = (const float*)d_in[1];
  const float* sym_flag = (const float*)d_in[2];
  float* out = (float*)d_out;

  const int B = in_sizes[2];            // 16
  const int N = in_sizes[0] / (B * 3);  // 2048

  // Pick TC: tcSize = N/TC must be even and <=256; ws must fit pmin.
  int TC = 32;
  while (TC > 1 && ((size_t)TC * B * N + B) * sizeof(float) > ws_size) TC >>= 1;
  while (N / TC > 256) TC <<= 1;

  float* pmin = (float*)d_ws;                       // [TC][B][N]
  float* psumAsym = pmin + (size_t)TC * B * N;      // [B]

  const int gridA = B * TC;  // 512 at TC=32
  chamfer_min_kernel<<<gridA, TPB, 0, stream>>>(pred, targ, pmin, psumAsym,
                                                out, N, B, TC);

  const int blocksPerBatch = N / TPB;  // 8
  chamfer_reduce_kernel<<<B * blocksPerBatch, TPB, 0, stream>>>(
      pmin, psumAsym, sym_flag, out, N, B, TC, blocksPerBatch,
      1.0f / (float)(N * B));
}